// Round 18
// baseline (653.285 us; speedup 1.0000x reference)
//
#include <hip/hip_runtime.h>
#include <hip/hip_bf16.h>
#include <stdint.h>

// feat (d_ws): NHWC f16 [8][256][256][128]. Physical channel order:
//   phys 0..31 = x1, 32..63 = x2, 64..95 = x3, 96..126 = x4, 127 = x.
// Logical (reference) ic: 0 -> phys127, ic>=1 -> phys ic-1.
// x45 (d_ws): NHWC f16 [4][256][256][128] (per 4-sample pass).
// wgen layout: [b][tap(49)][ch(128)].

typedef _Float16 f16;
typedef _Float16 f16x2 __attribute__((ext_vector_type(2)));
typedef _Float16 f16x8 __attribute__((ext_vector_type(8)));
typedef float f32x16 __attribute__((ext_vector_type(16)));

#define IMG 256
#define HW 65536
#define CH 128

static __device__ __forceinline__ size_t fidx(int b, int h, int w) {
    return (((size_t)b * IMG + h) * IMG + w) * CH;
}

__global__ __launch_bounds__(256) void prep_wt_k(const float* __restrict__ src,
                                                 f16* __restrict__ dst,
                                                 int Cin, int COUT) {
    int idx = blockIdx.x * 256 + threadIdx.x;
    if (idx >= 9 * 32 * 128) return;
    int tap = idx >> 12;
    int oc  = (idx >> 7) & 31;
    int pc  = idx & 127;
    int ic  = (pc == 127) ? 0 : pc + 1;
    float v = 0.f;
    if (oc < COUT && ic < Cin) v = src[(oc * Cin + ic) * 9 + tap];
    dst[idx] = (f16)v;
}

__global__ __launch_bounds__(256) void conv1_k(const float* __restrict__ x,
                                               f16* __restrict__ feat,
                                               const float* __restrict__ w,
                                               const float* __restrict__ bias) {
    int wx = threadIdx.x, h = blockIdx.x & 255, b = blockIdx.x >> 8;
    const float* p = x + (size_t)b * HW + h * IMG;
    bool hm = h > 0, hp = h < 255, wm = wx > 0, wp = wx < 255;
    float v[9];
    v[0] = (hm && wm) ? p[wx - 1 - IMG] : 0.f;
    v[1] = hm ? p[wx - IMG] : 0.f;
    v[2] = (hm && wp) ? p[wx + 1 - IMG] : 0.f;
    v[3] = wm ? p[wx - 1] : 0.f;
    v[4] = p[wx];
    v[5] = wp ? p[wx + 1] : 0.f;
    v[6] = (hp && wm) ? p[wx - 1 + IMG] : 0.f;
    v[7] = hp ? p[wx + IMG] : 0.f;
    v[8] = (hp && wp) ? p[wx + 1 + IMG] : 0.f;

    float acc[32];
#pragma unroll
    for (int oc = 0; oc < 32; ++oc) {
        float s = bias[oc];
#pragma unroll
        for (int k = 0; k < 9; ++k) s = fmaf(v[k], w[oc * 9 + k], s);
        acc[oc] = (s >= 0.f) ? s : 0.2f * s;
    }
    f16* op = feat + fidx(b, h, wx);
#pragma unroll
    for (int oc = 0; oc < 32; oc += 2) {
        f16x2 pr = {(f16)acc[oc], (f16)acc[oc + 1]};
        *(f16x2*)(op + oc) = pr;
    }
    op[127] = (f16)v[4];
}

// ---- implicit-GEMM conv: 16 rows x 32 px tile, global_load_lds staging ----
// LDS tile: 18 rows x 34 slots x 32 ch f16 = 39168 B. Content mapping:
// linear unit u=(r,slot,cgl) holds global c-group cgl ^ ((slot>>1)&3) —
// the same involution the swizzled reads apply, so reads are unchanged.
#define NSTT 10
#define STT (18 * 34 * 32)

typedef const uint32_t __attribute__((address_space(1)))* gas1_t;
typedef uint32_t __attribute__((address_space(3)))* las3_t;

// One-time: zero LDS cells whose (r,slot) fall outside the image.
__device__ __forceinline__ void zero_oob_t(f16* __restrict__ St,
                                           int r0, int w0, int tid) {
    bool edge = (r0 == 0) || (r0 == 240) || (w0 == 0) || (w0 == 224);
    if (edge) {
        f16x8 z = {};
#pragma unroll
        for (int it = 0; it < NSTT; ++it) {
            int u = tid + it * 256;
            if (u < 2448) {
                int r = u / 136, rem = u - r * 136;
                int slot = rem >> 2;
                int gh = r0 - 1 + r, gw = w0 - 1 + slot;
                if (!((unsigned)gh < 256u && (unsigned)gw < 256u))
                    *(f16x8*)(St + (size_t)u * 8) = z;
            }
        }
    }
}

// Stage one 32-ch chunk via global_load_lds width=16 (no VGPR round-trip).
// LDS dest: wave-uniform base + lane*16 (linear); source pre-swizzled.
__device__ __forceinline__ void stage_gll_t(const f16* __restrict__ src,
                                            f16* __restrict__ St,
                                            int b, int r0, int w0, int c0,
                                            int wave, int lane) {
#pragma unroll
    for (int it = 0; it < NSTT; ++it) {
        int ubase = it * 256 + wave * 64;          // wave-uniform
        int u = ubase + lane;
        f16* lp = St + (size_t)ubase * 8;          // HW adds lane*16
        if (u < 2448) {
            int r = u / 136, rem = u - r * 136;
            int slot = rem >> 2, cgl = rem & 3;
            int cg = cgl ^ ((slot >> 1) & 3);      // pre-swizzled source
            int gh = r0 - 1 + r, gw = w0 - 1 + slot;
            if ((unsigned)gh < 256u && (unsigned)gw < 256u) {
                const f16* gp = src + fidx(b, gh, gw) + c0 + cg * 8;
                __builtin_amdgcn_global_load_lds((gas1_t)gp, (las3_t)lp, 16, 0, 0);
            }
        }
    }
}

// Per-chunk MFMA: wave = out-rows wave*4..wave*4+3 at 32-px slot.
// kx outer; rolling 3-row B window (R15-proven compute).
__device__ __forceinline__ void compute_t(const f16* __restrict__ St,
                                          const f16* __restrict__ Wt, int c0,
                                          int wave, int l31, int g,
                                          f32x16* acc) {
#pragma unroll
    for (int kx = 0; kx < 3; ++kx) {
        f16x8 A0[3], A1[3];
#pragma unroll
        for (int ky = 0; ky < 3; ++ky) {
            const f16* wp = Wt + ((ky * 3 + kx) * 32 + l31) * 128 + c0 + g * 8;
            A0[ky] = *(const f16x8*)(wp);
            A1[ky] = *(const f16x8*)(wp + 16);
        }
        int slot = l31 + kx;
        int sw = (slot >> 1) & 3;
        int base = wave * 4;
        f16x8 B0[3], B1[3];
#pragma unroll
        for (int i = 0; i < 2; ++i) {
            int rb = ((base + i) * 34 + slot) * 4;
            B0[i] = *(const f16x8*)(St + (rb + ((0 + g) ^ sw)) * 8);
            B1[i] = *(const f16x8*)(St + (rb + ((2 + g) ^ sw)) * 8);
        }
#pragma unroll
        for (int r = 0; r < 4; ++r) {
            int rb = ((base + r + 2) * 34 + slot) * 4;
            B0[(r + 2) % 3] = *(const f16x8*)(St + (rb + ((0 + g) ^ sw)) * 8);
            B1[(r + 2) % 3] = *(const f16x8*)(St + (rb + ((2 + g) ^ sw)) * 8);
#pragma unroll
            for (int ky = 0; ky < 3; ++ky) {
                acc[r] = __builtin_amdgcn_mfma_f32_32x32x16_f16(A0[ky], B0[(r + ky) % 3], acc[r], 0, 0, 0);
                acc[r] = __builtin_amdgcn_mfma_f32_32x32x16_f16(A1[ky], B1[(r + ky) % 3], acc[r], 0, 0, 0);
            }
        }
    }
}

// Implicit-GEMM 3x3 conv. Block = 32 oc x (16 rows x 32 px), 39.2 KB LDS,
// 4 blocks/CU. sample = blockIdx&7 (XCD-affine).
__global__ __launch_bounds__(256, 4) void convm_k(f16* __restrict__ feat,
                                                  const f16* __restrict__ Wt,
                                                  const float* __restrict__ bias,
                                                  int outbase, int cmask, int COUT) {
    __shared__ f16 St[STT];
    int tid = threadIdx.x;
    int wave = tid >> 6, lane = tid & 63;
    int l31 = lane & 31, g = lane >> 5;
    int bi = blockIdx.x;
    int b = bi & 7;
    int tile = bi >> 3;                 // 0..127 = 16 row-tiles x 8 px-tiles
    int pxt = tile & 7, rt = tile >> 3;
    int r0 = rt * 16;
    int w0 = pxt * 32;
    f32x16 acc[4] = {{}, {}, {}, {}};

    zero_oob_t(St, r0, w0, tid);
    __syncthreads();

    for (int ck = 0; ck < 4; ++ck) {
        if (!((cmask >> ck) & 1)) continue;
        int c0 = ck * 32;
        stage_gll_t(feat, St, b, r0, w0, c0, wave, lane);
        __syncthreads();
        compute_t(St, Wt, c0, wave, l31, g, acc);
        __syncthreads();
    }

    int px = w0 + l31;
#pragma unroll
    for (int r = 0; r < 4; ++r) {
        f16* op = feat + fidx(b, r0 + wave * 4 + r, px) + outbase;
#pragma unroll
        for (int q = 0; q < 16; q += 2) {
            int oc0 = (q & 3) + 8 * (q >> 2) + 4 * g;
            float b0v = bias[oc0];
            float b1v = (oc0 + 1 < COUT) ? bias[oc0 + 1] : 0.f;
            float v0 = acc[r][q] + b0v;
            float v1 = acc[r][q + 1] + b1v;
            v0 = (v0 >= 0.f) ? v0 : 0.2f * v0;
            v1 = (v1 >= 0.f) ? v1 : 0.2f * v1;
            if (oc0 + 1 < COUT) {
                f16x2 pr = {(f16)v0, (f16)v1};
                *(f16x2*)(op + oc0) = pr;
            } else if (oc0 < COUT) {
                op[oc0] = (f16)v0;
            }
        }
    }
}

// conv5 over x45 (4-sample buffer), fp32 out, no act. Same structure.
__global__ __launch_bounds__(256, 4) void convm_out_k(const f16* __restrict__ x45,
                                                      const f16* __restrict__ Wt,
                                                      const float* __restrict__ bias,
                                                      float* __restrict__ out,
                                                      int b0) {
    __shared__ f16 St[STT];
    int tid = threadIdx.x;
    int wave = tid >> 6, lane = tid & 63;
    int l31 = lane & 31, g = lane >> 5;
    int bi = blockIdx.x;
    int bl = bi & 3;
    int tile = bi >> 2;                 // 0..127
    int pxt = tile & 7, rt = tile >> 3;
    int r0 = rt * 16;
    int w0 = pxt * 32;
    f32x16 acc[4] = {{}, {}, {}, {}};

    zero_oob_t(St, r0, w0, tid);
    __syncthreads();

    for (int ck = 0; ck < 4; ++ck) {
        int c0 = ck * 32;
        stage_gll_t(x45, St, bl, r0, w0, c0, wave, lane);
        __syncthreads();
        compute_t(St, Wt, c0, wave, l31, g, acc);
        __syncthreads();
    }

    if (g == 0) {
        int gb = b0 + bl;
        int px = w0 + l31;
#pragma unroll
        for (int r = 0; r < 4; ++r) {
#pragma unroll
            for (int oc = 0; oc < 3; ++oc) {
                float vv = acc[r][oc] + bias[oc];
                out[((size_t)(gb * 3 + oc)) * HW
                    + (size_t)(r0 + wave * 4 + r) * IMG + px] = vv;
            }
        }
    }
}

// Dynamic 7x7 depthwise + bias + lrelu (proven in R9/R10).
__global__ __launch_bounds__(256, 4) void dw_k(const f16* __restrict__ feat,
                                               const float* __restrict__ wgen,
                                               const float* __restrict__ dwb,
                                               f16* __restrict__ x45,
                                               int b0) {
    int tid = threadIdx.x;
    int lane = tid & 63;
    int wv = tid >> 6;
    int c = (wv & 1) * 64 + lane;
    int colh = wv >> 1;

    int bi = blockIdx.x;
    int ct = bi & 31;
    int t2 = bi >> 5;
    int vt = t2 & 7;
    int bl = t2 >> 3;
    int gb = b0 + bl;
    int x0 = ct * 8 + colh * 4;
    int y0 = vt * 32;

    int lc = (c == 127) ? 0 : c + 1;
    const float* wp = wgen + gb * 6272 + lc;
    f16x2 wp2[7][4];
#pragma unroll
    for (int k = 0; k < 7; ++k) {
#pragma unroll
        for (int p = 0; p < 3; ++p) {
            f16x2 t = {(f16)wp[(k * 7 + 2 * p) * 128],
                       (f16)wp[(k * 7 + 2 * p + 1) * 128]};
            wp2[k][p] = t;
        }
        f16x2 t3 = {(f16)wp[(k * 7 + 6) * 128], (f16)0.f};
        wp2[k][3] = t3;
    }
    float bias = dwb[lc];

    const f16* fb = feat + (size_t)gb * HW * CH + c;
    f16* xb = x45 + (size_t)bl * HW * CH + c;

    int xo[10];
    bool xm[10];
#pragma unroll
    for (int i = 0; i < 10; ++i) {
        int gx = x0 - 3 + i;
        xm[i] = (unsigned)gx < 256u;
        int cx = gx < 0 ? 0 : (gx > 255 ? 255 : gx);
        xo[i] = cx * CH;
    }

    float a[7][4] = {};

    for (int yi = 0; yi < 40; yi += 2) {
        int gy0 = y0 - 3 + yi, gy1 = gy0 + 1;
        bool ym0 = (unsigned)gy0 < 256u, ym1 = (unsigned)gy1 < 256u;
        int cy0 = gy0 < 0 ? 0 : (gy0 > 255 ? 255 : gy0);
        int cy1 = gy1 < 0 ? 0 : (gy1 > 255 ? 255 : gy1);
        const f16* r0 = fb + (size_t)cy0 * IMG * CH;
        const f16* r1 = fb + (size_t)cy1 * IMG * CH;

        f16 u0[10], u1[10];
#pragma unroll
        for (int i = 0; i < 10; ++i) u0[i] = r0[xo[i]];
#pragma unroll
        for (int i = 0; i < 10; ++i) u1[i] = r1[xo[i]];
#pragma unroll
        for (int i = 0; i < 10; ++i) {
            if (!(ym0 && xm[i])) u0[i] = (f16)0.f;
            if (!(ym1 && xm[i])) u1[i] = (f16)0.f;
        }

        {
            f16x2 pe[5], po[5];
#pragma unroll
            for (int p = 0; p < 5; ++p) { f16x2 t = {u0[2 * p], u0[2 * p + 1]}; pe[p] = t; }
#pragma unroll
            for (int p = 0; p < 4; ++p) { f16x2 t = {u0[2 * p + 1], u0[2 * p + 2]}; po[p] = t; }
            { f16x2 t = {u0[9], (f16)0.f}; po[4] = t; }
#pragma unroll
            for (int k = 0; k < 7; ++k) {
                const int wr = 6 - k;
#pragma unroll
                for (int p = 0; p < 4; ++p) {
                    a[k][0] = __builtin_amdgcn_fdot2(pe[p],     wp2[wr][p], a[k][0], false);
                    a[k][1] = __builtin_amdgcn_fdot2(po[p],     wp2[wr][p], a[k][1], false);
                    a[k][2] = __builtin_amdgcn_fdot2(pe[p + 1], wp2[wr][p], a[k][2], false);
                    a[k][3] = __builtin_amdgcn_fdot2(po[p + 1], wp2[wr][p], a[k][3], false);
                }
            }
            if (yi >= 6 && yi < 38) {
                int yo = y0 + yi - 6;
#pragma unroll
                for (int j = 0; j < 4; ++j) {
                    float s = a[0][j] + bias;
                    s = (s >= 0.f) ? s : 0.2f * s;
                    xb[((size_t)yo * IMG + x0 + j) * CH] = (f16)s;
                }
            }
#pragma unroll
            for (int k = 0; k < 6; ++k)
#pragma unroll
                for (int j = 0; j < 4; ++j) a[k][j] = a[k + 1][j];
#pragma unroll
            for (int j = 0; j < 4; ++j) a[6][j] = 0.f;
        }

        {
            f16x2 pe[5], po[5];
#pragma unroll
            for (int p = 0; p < 5; ++p) { f16x2 t = {u1[2 * p], u1[2 * p + 1]}; pe[p] = t; }
#pragma unroll
            for (int p = 0; p < 4; ++p) { f16x2 t = {u1[2 * p + 1], u1[2 * p + 2]}; po[p] = t; }
            { f16x2 t = {u1[9], (f16)0.f}; po[4] = t; }
#pragma unroll
            for (int k = 0; k < 7; ++k) {
                const int wr = 6 - k;
#pragma unroll
                for (int p = 0; p < 4; ++p) {
                    a[k][0] = __builtin_amdgcn_fdot2(pe[p],     wp2[wr][p], a[k][0], false);
                    a[k][1] = __builtin_amdgcn_fdot2(po[p],     wp2[wr][p], a[k][1], false);
                    a[k][2] = __builtin_amdgcn_fdot2(pe[p + 1], wp2[wr][p], a[k][2], false);
                    a[k][3] = __builtin_amdgcn_fdot2(po[p + 1], wp2[wr][p], a[k][3], false);
                }
            }
            int yib = yi + 1;
            if (yib >= 6 && yib < 38) {
                int yo = y0 + yib - 6;
#pragma unroll
                for (int j = 0; j < 4; ++j) {
                    float s = a[0][j] + bias;
                    s = (s >= 0.f) ? s : 0.2f * s;
                    xb[((size_t)yo * IMG + x0 + j) * CH] = (f16)s;
                }
            }
#pragma unroll
            for (int k = 0; k < 6; ++k)
#pragma unroll
                for (int j = 0; j < 4; ++j) a[k][j] = a[k + 1][j];
#pragma unroll
            for (int j = 0; j < 4; ++j) a[6][j] = 0.f;
        }
    }
}

__global__ __launch_bounds__(256) void pool_part_k(const f16* __restrict__ feat,
                                                   float* __restrict__ part) {
    __shared__ float red[4][128];
    int bi = blockIdx.x;
    int b = bi >> 5, pb = bi & 31;
    int t = threadIdx.x;
    int cp = t & 63, ps = t >> 6;
    int px0 = pb * 2048 + ps * 512;
    float s0 = 0.f, s1 = 0.f;
    const f16* base = feat + (size_t)b * HW * CH + (size_t)px0 * CH + cp * 2;
    for (int i = 0; i < 512; ++i) {
        f16x2 v = *(const f16x2*)(base + (size_t)i * CH);
        s0 += (float)v[0];
        s1 += (float)v[1];
    }
    red[ps][cp * 2] = s0;
    red[ps][cp * 2 + 1] = s1;
    __syncthreads();
    if (t < 128) {
        float s = red[0][t] + red[1][t] + red[2][t] + red[3][t];
        part[((size_t)b * 32 + pb) * 128 + t] = s;
    }
}

__global__ __launch_bounds__(256) void pool_fin_k(const float* __restrict__ part,
                                                  float* __restrict__ pooled) {
    int gid = blockIdx.x * 256 + threadIdx.x;
    if (gid >= 1024) return;
    int b = gid >> 7, pc = gid & 127;
    float s = 0.f;
    for (int pb = 0; pb < 32; ++pb) s += part[((size_t)b * 32 + pb) * 128 + pc];
    int lc = (pc == 127) ? 0 : pc + 1;
    pooled[b * 128 + lc] = s * (1.f / 65536.f);
}

__global__ __launch_bounds__(256) void mlp1_k(const float* __restrict__ pooled,
                                              const float* __restrict__ w1,
                                              const float* __restrict__ g,
                                              const float* __restrict__ bb,
                                              float* __restrict__ hbuf) {
    int t = threadIdx.x;
    int b = t >> 5, r = t & 31;
    float s = 0.f;
    for (int c = 0; c < 128; ++c) s += pooled[b * 128 + c] * w1[r * 128 + c];
    s = s * g[r] + bb[r];
    hbuf[t] = (s > 0.f) ? s : 0.f;
}

__global__ __launch_bounds__(256) void mlp2_k(const float* __restrict__ hbuf,
                                              const float* __restrict__ w2,
                                              const float* __restrict__ b2,
                                              float* __restrict__ wgen) {
    int idx = blockIdx.x * 256 + threadIdx.x;
    if (idx >= 8 * 6272) return;
    int b = idx / 6272, i = idx - b * 6272;
    float s = b2[i];
    for (int r = 0; r < 32; ++r) s += hbuf[b * 32 + r] * w2[i * 32 + r];
    int lc = i / 49, tp = i - lc * 49;
    wgen[b * 6272 + tp * 128 + lc] = s;
}

extern "C" void kernel_launch(void* const* d_in, const int* in_sizes, int n_in,
                              void* d_out, int out_size, void* d_ws, size_t ws_size,
                              hipStream_t stream) {
    (void)in_sizes; (void)n_in; (void)out_size; (void)ws_size;
    const float* x     = (const float*)d_in[0];
    const float* c1w   = (const float*)d_in[1];
    const float* c1b   = (const float*)d_in[2];
    const float* c2w   = (const float*)d_in[3];
    const float* c2b   = (const float*)d_in[4];
    const float* c3w   = (const float*)d_in[5];
    const float* c3b   = (const float*)d_in[6];
    const float* c4w   = (const float*)d_in[7];
    const float* c4b   = (const float*)d_in[8];
    const float* dw_w1 = (const float*)d_in[9];
    const float* bn_g  = (const float*)d_in[10];
    const float* bn_b  = (const float*)d_in[11];
    const float* dw_w2 = (const float*)d_in[12];
    const float* dw_b2 = (const float*)d_in[13];
    const float* dwb   = (const float*)d_in[14];
    const float* c5w   = (const float*)d_in[15];
    const float* c5b   = (const float*)d_in[16];
    float* out = (float*)d_out;

    f16* feat = (f16*)d_ws;
    f16* x45  = feat + (size_t)8 * HW * CH;
    f16* Wt   = x45 + (size_t)4 * HW * CH;
    f16* Wt2 = Wt, *Wt3 = Wt + 36864, *Wt4 = Wt + 73728, *Wt5 = Wt + 110592;
    float* part   = (float*)(Wt + 4 * 36864);
    float* pooled = part + 8 * 32 * 128;
    float* hbuf   = pooled + 1024;
    float* wgen   = hbuf + 256;

    prep_wt_k<<<144, 256, 0, stream>>>(c2w, Wt2, 33, 32);
    prep_wt_k<<<144, 256, 0, stream>>>(c3w, Wt3, 65, 32);
    prep_wt_k<<<144, 256, 0, stream>>>(c4w, Wt4, 97, 31);
    prep_wt_k<<<144, 256, 0, stream>>>(c5w, Wt5, 128, 3);

    conv1_k<<<2048, 256, 0, stream>>>(x, feat, c1w, c1b);
    convm_k<<<1024, 256, 0, stream>>>(feat, Wt2, c2b, 32, 0b1001, 32);
    convm_k<<<1024, 256, 0, stream>>>(feat, Wt3, c3b, 64, 0b1011, 32);
    convm_k<<<1024, 256, 0, stream>>>(feat, Wt4, c4b, 96, 0b1111, 31);

    pool_part_k<<<256, 256, 0, stream>>>(feat, part);
    pool_fin_k<<<4, 256, 0, stream>>>(part, pooled);
    mlp1_k<<<1, 256, 0, stream>>>(pooled, dw_w1, bn_g, bn_b, hbuf);
    mlp2_k<<<196, 256, 0, stream>>>(hbuf, dw_w2, dw_b2, wgen);

    for (int b0 = 0; b0 < 8; b0 += 4) {
        dw_k<<<1024, 256, 0, stream>>>(feat, wgen, dwb, x45, b0);
        convm_out_k<<<512, 256, 0, stream>>>(x45, Wt5, c5b, out, b0);
    }
}

// Round 19
// 463.876 us; speedup vs baseline: 1.4083x; 1.4083x over previous
//
#include <hip/hip_runtime.h>
#include <hip/hip_bf16.h>

// feat (d_ws): NHWC f16 [8][256][256][128]. Physical channel order:
//   phys 0..31 = x1, 32..63 = x2, 64..95 = x3, 96..126 = x4, 127 = x.
// Logical (reference) ic: 0 -> phys127, ic>=1 -> phys ic-1.
// x45 (d_ws): NHWC f16 [4][256][256][128] (per 4-sample pass).
// wgen layout: [b][tap(49)][ch(128)].

typedef _Float16 f16;
typedef _Float16 f16x2 __attribute__((ext_vector_type(2)));
typedef _Float16 f16x8 __attribute__((ext_vector_type(8)));
typedef float f32x16 __attribute__((ext_vector_type(16)));

#define IMG 256
#define HW 65536
#define CH 128

static __device__ __forceinline__ size_t fidx(int b, int h, int w) {
    return (((size_t)b * IMG + h) * IMG + w) * CH;
}

__global__ __launch_bounds__(256) void prep_wt_k(const float* __restrict__ src,
                                                 f16* __restrict__ dst,
                                                 int Cin, int COUT) {
    int idx = blockIdx.x * 256 + threadIdx.x;
    if (idx >= 9 * 32 * 128) return;
    int tap = idx >> 12;
    int oc  = (idx >> 7) & 31;
    int pc  = idx & 127;
    int ic  = (pc == 127) ? 0 : pc + 1;
    float v = 0.f;
    if (oc < COUT && ic < Cin) v = src[(oc * Cin + ic) * 9 + tap];
    dst[idx] = (f16)v;
}

__global__ __launch_bounds__(256) void conv1_k(const float* __restrict__ x,
                                               f16* __restrict__ feat,
                                               const float* __restrict__ w,
                                               const float* __restrict__ bias) {
    int wx = threadIdx.x, h = blockIdx.x & 255, b = blockIdx.x >> 8;
    const float* p = x + (size_t)b * HW + h * IMG;
    bool hm = h > 0, hp = h < 255, wm = wx > 0, wp = wx < 255;
    float v[9];
    v[0] = (hm && wm) ? p[wx - 1 - IMG] : 0.f;
    v[1] = hm ? p[wx - IMG] : 0.f;
    v[2] = (hm && wp) ? p[wx + 1 - IMG] : 0.f;
    v[3] = wm ? p[wx - 1] : 0.f;
    v[4] = p[wx];
    v[5] = wp ? p[wx + 1] : 0.f;
    v[6] = (hp && wm) ? p[wx - 1 + IMG] : 0.f;
    v[7] = hp ? p[wx + IMG] : 0.f;
    v[8] = (hp && wp) ? p[wx + 1 + IMG] : 0.f;

    float acc[32];
#pragma unroll
    for (int oc = 0; oc < 32; ++oc) {
        float s = bias[oc];
#pragma unroll
        for (int k = 0; k < 9; ++k) s = fmaf(v[k], w[oc * 9 + k], s);
        acc[oc] = (s >= 0.f) ? s : 0.2f * s;
    }
    f16* op = feat + fidx(b, h, wx);
#pragma unroll
    for (int oc = 0; oc < 32; oc += 2) {
        f16x2 pr = {(f16)acc[oc], (f16)acc[oc + 1]};
        *(f16x2*)(op + oc) = pr;
    }
    op[127] = (f16)v[4];
}

// ---- implicit-GEMM conv: 16 rows x 32 px tile, DOUBLE-BUFFERED staging ----
// LDS tile: 2 x (18 rows x 34 slots x 32 ch) f16 = 2 x 39168 B.
#define NSTT 10
#define STT (18 * 34 * 32)

__device__ __forceinline__ void stage_issue_t(const f16* __restrict__ src,
                                              int b, int r0, int w0, int c0,
                                              int tid, f16x8* v) {
#pragma unroll
    for (int it = 0; it < NSTT; ++it) {
        int u = tid + it * 256;
        int r = u / 136, rem = u - r * 136;
        int slot = rem >> 2, cg = rem & 3;
        int gh = r0 - 1 + r, gw = w0 - 1 + slot;
        bool ok = (u < 2448) && ((unsigned)gh < 256u) && ((unsigned)gw < 256u);
        int ch = gh < 0 ? 0 : (gh > 255 ? 255 : gh);
        int cw = gw < 0 ? 0 : (gw > 255 ? 255 : gw);
        f16x8 t = *(const f16x8*)(src + fidx(b, ch, cw) + c0 + cg * 8);
        f16x8 z = {};
        v[it] = ok ? t : z;
    }
}

__device__ __forceinline__ void stage_write_t(f16* __restrict__ St, int tid,
                                              const f16x8* v) {
#pragma unroll
    for (int it = 0; it < NSTT; ++it) {
        int u = tid + it * 256;
        if (u < 2448) {
            int r = u / 136, rem = u - r * 136;
            int slot = rem >> 2, cg = rem & 3;
            *(f16x8*)(St + ((r * 34 + slot) * 4 + (cg ^ ((slot >> 1) & 3))) * 8) = v[it];
        }
    }
}

// Per-chunk MFMA: wave = out-rows wave*4..wave*4+3 at 32-px slot.
// kx outer; rolling 3-row B window; JIT A-fragment loads.
__device__ __forceinline__ void compute_t(const f16* __restrict__ St,
                                          const f16* __restrict__ Wt, int c0,
                                          int wave, int l31, int g,
                                          f32x16* acc) {
#pragma unroll
    for (int kx = 0; kx < 3; ++kx) {
        f16x8 A0[3], A1[3];
#pragma unroll
        for (int ky = 0; ky < 3; ++ky) {
            const f16* wp = Wt + ((ky * 3 + kx) * 32 + l31) * 128 + c0 + g * 8;
            A0[ky] = *(const f16x8*)(wp);
            A1[ky] = *(const f16x8*)(wp + 16);
        }
        int slot = l31 + kx;
        int sw = (slot >> 1) & 3;
        int base = wave * 4;
        f16x8 B0[3], B1[3];
#pragma unroll
        for (int i = 0; i < 2; ++i) {
            int rb = ((base + i) * 34 + slot) * 4;
            B0[i] = *(const f16x8*)(St + (rb + ((0 + g) ^ sw)) * 8);
            B1[i] = *(const f16x8*)(St + (rb + ((2 + g) ^ sw)) * 8);
        }
#pragma unroll
        for (int r = 0; r < 4; ++r) {
            int rb = ((base + r + 2) * 34 + slot) * 4;
            B0[(r + 2) % 3] = *(const f16x8*)(St + (rb + ((0 + g) ^ sw)) * 8);
            B1[(r + 2) % 3] = *(const f16x8*)(St + (rb + ((2 + g) ^ sw)) * 8);
#pragma unroll
            for (int ky = 0; ky < 3; ++ky) {
                acc[r] = __builtin_amdgcn_mfma_f32_32x32x16_f16(A0[ky], B0[(r + ky) % 3], acc[r], 0, 0, 0);
                acc[r] = __builtin_amdgcn_mfma_f32_32x32x16_f16(A1[ky], B1[(r + ky) % 3], acc[r], 0, 0, 0);
            }
        }
    }
}

// Implicit-GEMM 3x3 conv. Block = 32 oc x (16 rows x 32 px), 2x39.2 KB LDS
// double-buffered: next chunk's loads issue before current chunk's MFMAs.
// sample = blockIdx&7 (XCD-affine).
__global__ __launch_bounds__(256, 2) void convm_k(f16* __restrict__ feat,
                                                  const f16* __restrict__ Wt,
                                                  const float* __restrict__ bias,
                                                  int outbase, int cmask, int COUT) {
    __shared__ f16 St[2][STT];
    int tid = threadIdx.x;
    int wave = tid >> 6, lane = tid & 63;
    int l31 = lane & 31, g = lane >> 5;
    int bi = blockIdx.x;
    int b = bi & 7;
    int tile = bi >> 3;                 // 0..127 = 16 row-tiles x 8 px-tiles
    int pxt = tile & 7, rt = tile >> 3;
    int r0 = rt * 16;
    int w0 = pxt * 32;
    f32x16 acc[4] = {{}, {}, {}, {}};

    int cks[4], ncs = 0;
#pragma unroll
    for (int i = 0; i < 4; ++i)
        if ((cmask >> i) & 1) cks[ncs++] = i;

    {
        f16x8 v[NSTT];
        stage_issue_t(feat, b, r0, w0, cks[0] * 32, tid, v);
        stage_write_t(St[0], tid, v);
    }
    __syncthreads();

    for (int i = 0; i < ncs; ++i) {
        f16x8 vn[NSTT];
        if (i + 1 < ncs)
            stage_issue_t(feat, b, r0, w0, cks[i + 1] * 32, tid, vn); // in flight
        compute_t(St[i & 1], Wt, cks[i] * 32, wave, l31, g, acc);     // hides latency
        if (i + 1 < ncs)
            stage_write_t(St[(i + 1) & 1], tid, vn);
        __syncthreads();
    }

    int px = w0 + l31;
#pragma unroll
    for (int r = 0; r < 4; ++r) {
        f16* op = feat + fidx(b, r0 + wave * 4 + r, px) + outbase;
#pragma unroll
        for (int q = 0; q < 16; q += 2) {
            int oc0 = (q & 3) + 8 * (q >> 2) + 4 * g;
            float b0v = bias[oc0];
            float b1v = (oc0 + 1 < COUT) ? bias[oc0 + 1] : 0.f;
            float v0 = acc[r][q] + b0v;
            float v1 = acc[r][q + 1] + b1v;
            v0 = (v0 >= 0.f) ? v0 : 0.2f * v0;
            v1 = (v1 >= 0.f) ? v1 : 0.2f * v1;
            if (oc0 + 1 < COUT) {
                f16x2 pr = {(f16)v0, (f16)v1};
                *(f16x2*)(op + oc0) = pr;
            } else if (oc0 < COUT) {
                op[oc0] = (f16)v0;
            }
        }
    }
}

// conv5 over x45 (4-sample buffer), fp32 out, no act. Same dbuf structure.
__global__ __launch_bounds__(256, 2) void convm_out_k(const f16* __restrict__ x45,
                                                      const f16* __restrict__ Wt,
                                                      const float* __restrict__ bias,
                                                      float* __restrict__ out,
                                                      int b0) {
    __shared__ f16 St[2][STT];
    int tid = threadIdx.x;
    int wave = tid >> 6, lane = tid & 63;
    int l31 = lane & 31, g = lane >> 5;
    int bi = blockIdx.x;
    int bl = bi & 3;
    int tile = bi >> 2;                 // 0..127
    int pxt = tile & 7, rt = tile >> 3;
    int r0 = rt * 16;
    int w0 = pxt * 32;
    f32x16 acc[4] = {{}, {}, {}, {}};

    {
        f16x8 v[NSTT];
        stage_issue_t(x45, bl, r0, w0, 0, tid, v);
        stage_write_t(St[0], tid, v);
    }
    __syncthreads();

    for (int i = 0; i < 4; ++i) {
        f16x8 vn[NSTT];
        if (i + 1 < 4)
            stage_issue_t(x45, bl, r0, w0, (i + 1) * 32, tid, vn);
        compute_t(St[i & 1], Wt, i * 32, wave, l31, g, acc);
        if (i + 1 < 4)
            stage_write_t(St[(i + 1) & 1], tid, vn);
        __syncthreads();
    }

    if (g == 0) {
        int gb = b0 + bl;
        int px = w0 + l31;
#pragma unroll
        for (int r = 0; r < 4; ++r) {
#pragma unroll
            for (int oc = 0; oc < 3; ++oc) {
                float vv = acc[r][oc] + bias[oc];
                out[((size_t)(gb * 3 + oc)) * HW
                    + (size_t)(r0 + wave * 4 + r) * IMG + px] = vv;
            }
        }
    }
}

// Dynamic 7x7 depthwise + bias + lrelu (proven in R9/R10).
__global__ __launch_bounds__(256, 4) void dw_k(const f16* __restrict__ feat,
                                               const float* __restrict__ wgen,
                                               const float* __restrict__ dwb,
                                               f16* __restrict__ x45,
                                               int b0) {
    int tid = threadIdx.x;
    int lane = tid & 63;
    int wv = tid >> 6;
    int c = (wv & 1) * 64 + lane;
    int colh = wv >> 1;

    int bi = blockIdx.x;
    int ct = bi & 31;
    int t2 = bi >> 5;
    int vt = t2 & 7;
    int bl = t2 >> 3;
    int gb = b0 + bl;
    int x0 = ct * 8 + colh * 4;
    int y0 = vt * 32;

    int lc = (c == 127) ? 0 : c + 1;
    const float* wp = wgen + gb * 6272 + lc;
    f16x2 wp2[7][4];
#pragma unroll
    for (int k = 0; k < 7; ++k) {
#pragma unroll
        for (int p = 0; p < 3; ++p) {
            f16x2 t = {(f16)wp[(k * 7 + 2 * p) * 128],
                       (f16)wp[(k * 7 + 2 * p + 1) * 128]};
            wp2[k][p] = t;
        }
        f16x2 t3 = {(f16)wp[(k * 7 + 6) * 128], (f16)0.f};
        wp2[k][3] = t3;
    }
    float bias = dwb[lc];

    const f16* fb = feat + (size_t)gb * HW * CH + c;
    f16* xb = x45 + (size_t)bl * HW * CH + c;

    int xo[10];
    bool xm[10];
#pragma unroll
    for (int i = 0; i < 10; ++i) {
        int gx = x0 - 3 + i;
        xm[i] = (unsigned)gx < 256u;
        int cx = gx < 0 ? 0 : (gx > 255 ? 255 : gx);
        xo[i] = cx * CH;
    }

    float a[7][4] = {};

    for (int yi = 0; yi < 40; yi += 2) {
        int gy0 = y0 - 3 + yi, gy1 = gy0 + 1;
        bool ym0 = (unsigned)gy0 < 256u, ym1 = (unsigned)gy1 < 256u;
        int cy0 = gy0 < 0 ? 0 : (gy0 > 255 ? 255 : gy0);
        int cy1 = gy1 < 0 ? 0 : (gy1 > 255 ? 255 : gy1);
        const f16* r0 = fb + (size_t)cy0 * IMG * CH;
        const f16* r1 = fb + (size_t)cy1 * IMG * CH;

        f16 u0[10], u1[10];
#pragma unroll
        for (int i = 0; i < 10; ++i) u0[i] = r0[xo[i]];
#pragma unroll
        for (int i = 0; i < 10; ++i) u1[i] = r1[xo[i]];
#pragma unroll
        for (int i = 0; i < 10; ++i) {
            if (!(ym0 && xm[i])) u0[i] = (f16)0.f;
            if (!(ym1 && xm[i])) u1[i] = (f16)0.f;
        }

        {
            f16x2 pe[5], po[5];
#pragma unroll
            for (int p = 0; p < 5; ++p) { f16x2 t = {u0[2 * p], u0[2 * p + 1]}; pe[p] = t; }
#pragma unroll
            for (int p = 0; p < 4; ++p) { f16x2 t = {u0[2 * p + 1], u0[2 * p + 2]}; po[p] = t; }
            { f16x2 t = {u0[9], (f16)0.f}; po[4] = t; }
#pragma unroll
            for (int k = 0; k < 7; ++k) {
                const int wr = 6 - k;
#pragma unroll
                for (int p = 0; p < 4; ++p) {
                    a[k][0] = __builtin_amdgcn_fdot2(pe[p],     wp2[wr][p], a[k][0], false);
                    a[k][1] = __builtin_amdgcn_fdot2(po[p],     wp2[wr][p], a[k][1], false);
                    a[k][2] = __builtin_amdgcn_fdot2(pe[p + 1], wp2[wr][p], a[k][2], false);
                    a[k][3] = __builtin_amdgcn_fdot2(po[p + 1], wp2[wr][p], a[k][3], false);
                }
            }
            if (yi >= 6 && yi < 38) {
                int yo = y0 + yi - 6;
#pragma unroll
                for (int j = 0; j < 4; ++j) {
                    float s = a[0][j] + bias;
                    s = (s >= 0.f) ? s : 0.2f * s;
                    xb[((size_t)yo * IMG + x0 + j) * CH] = (f16)s;
                }
            }
#pragma unroll
            for (int k = 0; k < 6; ++k)
#pragma unroll
                for (int j = 0; j < 4; ++j) a[k][j] = a[k + 1][j];
#pragma unroll
            for (int j = 0; j < 4; ++j) a[6][j] = 0.f;
        }

        {
            f16x2 pe[5], po[5];
#pragma unroll
            for (int p = 0; p < 5; ++p) { f16x2 t = {u1[2 * p], u1[2 * p + 1]}; pe[p] = t; }
#pragma unroll
            for (int p = 0; p < 4; ++p) { f16x2 t = {u1[2 * p + 1], u1[2 * p + 2]}; po[p] = t; }
            { f16x2 t = {u1[9], (f16)0.f}; po[4] = t; }
#pragma unroll
            for (int k = 0; k < 7; ++k) {
                const int wr = 6 - k;
#pragma unroll
                for (int p = 0; p < 4; ++p) {
                    a[k][0] = __builtin_amdgcn_fdot2(pe[p],     wp2[wr][p], a[k][0], false);
                    a[k][1] = __builtin_amdgcn_fdot2(po[p],     wp2[wr][p], a[k][1], false);
                    a[k][2] = __builtin_amdgcn_fdot2(pe[p + 1], wp2[wr][p], a[k][2], false);
                    a[k][3] = __builtin_amdgcn_fdot2(po[p + 1], wp2[wr][p], a[k][3], false);
                }
            }
            int yib = yi + 1;
            if (yib >= 6 && yib < 38) {
                int yo = y0 + yib - 6;
#pragma unroll
                for (int j = 0; j < 4; ++j) {
                    float s = a[0][j] + bias;
                    s = (s >= 0.f) ? s : 0.2f * s;
                    xb[((size_t)yo * IMG + x0 + j) * CH] = (f16)s;
                }
            }
#pragma unroll
            for (int k = 0; k < 6; ++k)
#pragma unroll
                for (int j = 0; j < 4; ++j) a[k][j] = a[k + 1][j];
#pragma unroll
            for (int j = 0; j < 4; ++j) a[6][j] = 0.f;
        }
    }
}

__global__ __launch_bounds__(256) void pool_part_k(const f16* __restrict__ feat,
                                                   float* __restrict__ part) {
    __shared__ float red[4][128];
    int bi = blockIdx.x;
    int b = bi >> 5, pb = bi & 31;
    int t = threadIdx.x;
    int cp = t & 63, ps = t >> 6;
    int px0 = pb * 2048 + ps * 512;
    float s0 = 0.f, s1 = 0.f;
    const f16* base = feat + (size_t)b * HW * CH + (size_t)px0 * CH + cp * 2;
    for (int i = 0; i < 512; ++i) {
        f16x2 v = *(const f16x2*)(base + (size_t)i * CH);
        s0 += (float)v[0];
        s1 += (float)v[1];
    }
    red[ps][cp * 2] = s0;
    red[ps][cp * 2 + 1] = s1;
    __syncthreads();
    if (t < 128) {
        float s = red[0][t] + red[1][t] + red[2][t] + red[3][t];
        part[((size_t)b * 32 + pb) * 128 + t] = s;
    }
}

__global__ __launch_bounds__(256) void pool_fin_k(const float* __restrict__ part,
                                                  float* __restrict__ pooled) {
    int gid = blockIdx.x * 256 + threadIdx.x;
    if (gid >= 1024) return;
    int b = gid >> 7, pc = gid & 127;
    float s = 0.f;
    for (int pb = 0; pb < 32; ++pb) s += part[((size_t)b * 32 + pb) * 128 + pc];
    int lc = (pc == 127) ? 0 : pc + 1;
    pooled[b * 128 + lc] = s * (1.f / 65536.f);
}

__global__ __launch_bounds__(256) void mlp1_k(const float* __restrict__ pooled,
                                              const float* __restrict__ w1,
                                              const float* __restrict__ g,
                                              const float* __restrict__ bb,
                                              float* __restrict__ hbuf) {
    int t = threadIdx.x;
    int b = t >> 5, r = t & 31;
    float s = 0.f;
    for (int c = 0; c < 128; ++c) s += pooled[b * 128 + c] * w1[r * 128 + c];
    s = s * g[r] + bb[r];
    hbuf[t] = (s > 0.f) ? s : 0.f;
}

__global__ __launch_bounds__(256) void mlp2_k(const float* __restrict__ hbuf,
                                              const float* __restrict__ w2,
                                              const float* __restrict__ b2,
                                              float* __restrict__ wgen) {
    int idx = blockIdx.x * 256 + threadIdx.x;
    if (idx >= 8 * 6272) return;
    int b = idx / 6272, i = idx - b * 6272;
    float s = b2[i];
    for (int r = 0; r < 32; ++r) s += hbuf[b * 32 + r] * w2[i * 32 + r];
    int lc = i / 49, tp = i - lc * 49;
    wgen[b * 6272 + tp * 128 + lc] = s;
}

extern "C" void kernel_launch(void* const* d_in, const int* in_sizes, int n_in,
                              void* d_out, int out_size, void* d_ws, size_t ws_size,
                              hipStream_t stream) {
    (void)in_sizes; (void)n_in; (void)out_size; (void)ws_size;
    const float* x     = (const float*)d_in[0];
    const float* c1w   = (const float*)d_in[1];
    const float* c1b   = (const float*)d_in[2];
    const float* c2w   = (const float*)d_in[3];
    const float* c2b   = (const float*)d_in[4];
    const float* c3w   = (const float*)d_in[5];
    const float* c3b   = (const float*)d_in[6];
    const float* c4w   = (const float*)d_in[7];
    const float* c4b   = (const float*)d_in[8];
    const float* dw_w1 = (const float*)d_in[9];
    const float* bn_g  = (const float*)d_in[10];
    const float* bn_b  = (const float*)d_in[11];
    const float* dw_w2 = (const float*)d_in[12];
    const float* dw_b2 = (const float*)d_in[13];
    const float* dwb   = (const float*)d_in[14];
    const float* c5w   = (const float*)d_in[15];
    const float* c5b   = (const float*)d_in[16];
    float* out = (float*)d_out;

    f16* feat = (f16*)d_ws;
    f16* x45  = feat + (size_t)8 * HW * CH;
    f16* Wt   = x45 + (size_t)4 * HW * CH;
    f16* Wt2 = Wt, *Wt3 = Wt + 36864, *Wt4 = Wt + 73728, *Wt5 = Wt + 110592;
    float* part   = (float*)(Wt + 4 * 36864);
    float* pooled = part + 8 * 32 * 128;
    float* hbuf   = pooled + 1024;
    float* wgen   = hbuf + 256;

    prep_wt_k<<<144, 256, 0, stream>>>(c2w, Wt2, 33, 32);
    prep_wt_k<<<144, 256, 0, stream>>>(c3w, Wt3, 65, 32);
    prep_wt_k<<<144, 256, 0, stream>>>(c4w, Wt4, 97, 31);
    prep_wt_k<<<144, 256, 0, stream>>>(c5w, Wt5, 128, 3);

    conv1_k<<<2048, 256, 0, stream>>>(x, feat, c1w, c1b);
    convm_k<<<1024, 256, 0, stream>>>(feat, Wt2, c2b, 32, 0b1001, 32);
    convm_k<<<1024, 256, 0, stream>>>(feat, Wt3, c3b, 64, 0b1011, 32);
    convm_k<<<1024, 256, 0, stream>>>(feat, Wt4, c4b, 96, 0b1111, 31);

    pool_part_k<<<256, 256, 0, stream>>>(feat, part);
    pool_fin_k<<<4, 256, 0, stream>>>(part, pooled);
    mlp1_k<<<1, 256, 0, stream>>>(pooled, dw_w1, bn_g, bn_b, hbuf);
    mlp2_k<<<196, 256, 0, stream>>>(hbuf, dw_w2, dw_b2, wgen);

    for (int b0 = 0; b0 < 8; b0 += 4) {
        dw_k<<<1024, 256, 0, stream>>>(feat, wgen, dwb, x45, b0);
        convm_out_k<<<512, 256, 0, stream>>>(x45, Wt5, c5b, out, b0);
    }
}